// Round 11
// baseline (131.326 us; speedup 1.0000x reference)
//
#include <hip/hip_runtime.h>
#include <stdint.h>

typedef short bf16x8 __attribute__((ext_vector_type(8)));
typedef float f32x4 __attribute__((ext_vector_type(4)));

__device__ __forceinline__ unsigned short f2bf(float f) {
  uint32_t u = __float_as_uint(f);
  u = (u + 0x7FFFu + ((u >> 16) & 1u)) >> 16;
  return (unsigned short)u;
}
__device__ __forceinline__ float bf2f(unsigned short h) {
  return __uint_as_float(((uint32_t)h) << 16);
}

__device__ __forceinline__ void gload16(const void* g, void* lds) {
  const __attribute__((address_space(1))) char* gp =
      (const __attribute__((address_space(1))) char*)(uintptr_t)g;
  __attribute__((address_space(3))) char* sp =
      (__attribute__((address_space(3))) char*)(uint32_t)(uintptr_t)lds;
  __builtin_amdgcn_global_load_lds(gp, sp, 16, 0, 0);
}

// ---------------- fused fp32 -> bf16 converts (all 5 tensors, one dispatch) ----------------
__global__ void k_cvt_all(const float* __restrict__ x, const float* __restrict__ Wq,
                          const float* __restrict__ Wk, const float* __restrict__ Wv,
                          const float* __restrict__ Wo, unsigned short* __restrict__ xb,
                          unsigned short* __restrict__ Wcat, unsigned short* __restrict__ Wob) {
  int b = blockIdx.x;
  const float* src;
  unsigned short* dst;
  int off;
  if (b < 4096)       { src = x;  dst = xb;                  off = b; }
  else if (b < 8192)  { src = Wq; dst = Wcat;                off = b - 4096; }
  else if (b < 9216)  { src = Wk; dst = Wcat + 2048 * 2048;  off = b - 8192; }
  else if (b < 10240) { src = Wv; dst = Wcat + 2560 * 2048;  off = b - 9216; }
  else                { src = Wo; dst = Wob;                  off = b - 10240; }
  int i = off * 256 + threadIdx.x;
  float4 v = ((const float4*)src)[i];
  ushort4 o;
  o.x = f2bf(v.x); o.y = f2bf(v.y); o.z = f2bf(v.z); o.w = f2bf(v.w);
  ((ushort4*)dst)[i] = o;
}

// ---------------- bf16 GEMM, double-buffered: C[m][n] = sum_k A[m][k]*B[n][k] --------------
// ROPE=1 (gemm0): epilogue applies half-split RoPE in fp32 to Q (cols<2048, * scale*log2e)
// and K (2048<=col<2560); V region passthrough. Pair (t1,t2) = (acc[i][j], acc[i][j+2]).
template <int OUTF32, int ROPE>
__global__ __launch_bounds__(256) void k_gemm(const unsigned short* __restrict__ A,
                                              const unsigned short* __restrict__ B,
                                              void* __restrict__ Cout,
                                              int M, int N, int K,
                                              const float* __restrict__ scale_p) {
  __shared__ unsigned short As[2][128 * 64];
  __shared__ unsigned short Bs[2][128 * 64];
  const int tid = threadIdx.x;
  const int w = tid >> 6, lane = tid & 63;
  const int g = lane >> 4, cl = lane & 15;
  const int nTn = N >> 7;
  const int per = gridDim.x >> 3;
  const int bid = (blockIdx.x & 7) * per + (blockIdx.x >> 3);
  const int tm = bid / nTn, tn = bid % nTn;
  const int m0 = tm << 7, n0 = tn << 7;
  const int wm = (w >> 1) << 6, wn = (w & 1) << 6;
  f32x4 acc[4][4] = {};

  auto stage = [&](int kt, int b) {
#pragma unroll
    for (int it = 0; it < 8; ++it) {
      int cc = tid + it * 256;
      int half = cc >> 10;
      int c3 = cc & 1023;
      int row = c3 >> 3, kb = (c3 & 7) << 4;
      const unsigned short* base = half ? (B + (size_t)(n0 + row) * K + kt)
                                        : (A + (size_t)(m0 + row) * K + kt);
      const char* src = (const char*)base + (kb ^ ((row & 7) << 4));
      char* dstl = (char*)(half ? Bs[b] : As[b]) + c3 * 16;
      gload16(src, dstl);
    }
  };

  stage(0, 0);
  asm volatile("s_waitcnt vmcnt(0)" ::: "memory");
  __syncthreads();
  int buf = 0;

  for (int kt = 0; kt < K; kt += 64) {
    if (kt + 64 < K) stage(kt + 64, buf ^ 1);
#pragma unroll
    for (int ks = 0; ks < 2; ++ks) {
      bf16x8 af[4], bfr[4];
#pragma unroll
      for (int i = 0; i < 4; ++i) {
        int row = wm + i * 16 + cl;
        int kb = ((g << 4) + (ks << 6)) ^ ((row & 7) << 4);
        af[i] = *(const bf16x8*)((const char*)As[buf] + row * 128 + kb);
      }
#pragma unroll
      for (int j = 0; j < 4; ++j) {
        int row = wn + j * 16 + cl;
        int kb = ((g << 4) + (ks << 6)) ^ ((row & 7) << 4);
        bfr[j] = *(const bf16x8*)((const char*)Bs[buf] + row * 128 + kb);
      }
#pragma unroll
      for (int i = 0; i < 4; ++i)
#pragma unroll
        for (int j = 0; j < 4; ++j)
          acc[i][j] = __builtin_amdgcn_mfma_f32_16x16x32_bf16(af[i], bfr[j], acc[i][j], 0, 0, 0);
    }
    asm volatile("s_waitcnt vmcnt(0)" ::: "memory");
    __syncthreads();
    buf ^= 1;
  }

  if (ROPE && n0 < 2560) {
    float s0v = scale_p[0] * 0.125f * 1.4426950408889634f;
    float sc = (n0 < 2048) ? s0v : 1.0f;
    float invf[2];
#pragma unroll
    for (int j = 0; j < 2; ++j)
      invf[j] = __expf(-(float)(j * 16 + cl) * 0.2878231366242557f);
#pragma unroll
    for (int i = 0; i < 4; ++i)
#pragma unroll
      for (int r = 0; r < 4; ++r) {
        float pos = (float)(m0 + wm + i * 16 + (g << 2) + r);
#pragma unroll
        for (int j = 0; j < 2; ++j) {
          float ang = pos * invf[j];
          float sn, cs;
          __sincosf(ang, &sn, &cs);
          float t1 = acc[i][j][r], t2 = acc[i][j + 2][r];
          acc[i][j][r] = (t1 * cs - t2 * sn) * sc;
          acc[i][j + 2][r] = (t1 * sn + t2 * cs) * sc;
        }
      }
  }

#pragma unroll
  for (int i = 0; i < 4; ++i)
#pragma unroll
    for (int j = 0; j < 4; ++j)
#pragma unroll
      for (int r = 0; r < 4; ++r) {
        int row = m0 + wm + i * 16 + (g << 2) + r;
        int col = n0 + wn + j * 16 + cl;
        float v = acc[i][j][r];
        if (OUTF32)
          ((float*)Cout)[(size_t)row * N + col] = v;
        else
          ((unsigned short*)Cout)[(size_t)row * N + col] = f2bf(v);
      }
}

// ---------------- V transpose: VT[hk][d][l] from QKV V section ----------------
__global__ void k_vt(const unsigned short* __restrict__ qkv, unsigned short* __restrict__ vt) {
  __shared__ unsigned short tl[64][80];
  const int tid = threadIdx.x;
  const int hk = blockIdx.x >> 5, lt = blockIdx.x & 31;
  const int l0 = lt << 6;
#pragma unroll
  for (int it = 0; it < 2; ++it) {
    int cc = tid + it * 256;
    int lr = cc >> 3, d0 = (cc & 7) << 3;
    uint4 v = *(const uint4*)(qkv + (size_t)(l0 + lr) * 3072 + 2560 + hk * 64 + d0);
    *(uint4*)&tl[lr][d0] = v;
  }
  __syncthreads();
#pragma unroll
  for (int it = 0; it < 2; ++it) {
    int cc = tid + it * 256;
    int dr = cc >> 3, le = (cc & 7) << 3;
    unsigned short tmp[8] __attribute__((aligned(16)));
#pragma unroll
    for (int j = 0; j < 8; ++j) tmp[j] = tl[le + j][dr];
    *(uint4*)(vt + (size_t)(hk * 64 + dr) * 2048 + l0 + le) = *(const uint4*)tmp;
  }
}

// ---------------- Flash attention, split-KV: R10 engine over tile range [lo,hi) ----------
// qb>=16 split into 2 parts writing fp32 partials {acc,m,l}; qb<16 writes AO directly.
// Grid 1536 = 32h x (32 split-parts + 16 singles), near-uniform 8-17 tiles/block.
__global__ __launch_bounds__(256) void k_attn(const unsigned short* __restrict__ qkv,
                                              const unsigned short* __restrict__ vt,
                                              unsigned short* __restrict__ ao,
                                              float* __restrict__ partAcc,
                                              float* __restrict__ partML) {
  __shared__ unsigned short Ks[2][64 * 64];
  __shared__ unsigned short Vs[2][64 * 64];
  __shared__ unsigned short Ps[4 * 16 * 64];
  const int tid = threadIdx.x;
  const int w = tid >> 6, lane = tid & 63;
  const int g = lane >> 4, cl = lane & 15;
  const int b = blockIdx.x;
  const int h = b & 31;
  const int u = b >> 5;  // 0..47: 0-31 split parts (longest), 32-47 singles descending
  int qb, lo, hi, part;
  bool split;
  if (u < 32) {
    qb = 16 + (u >> 1);
    part = u & 1;
    int mid = (qb + 2) >> 1;
    lo = part ? mid : 0;
    hi = part ? (qb + 1) : mid;
    split = true;
  } else {
    qb = 47 - u;
    lo = 0;
    hi = qb + 1;
    split = false;
    part = 0;
  }
  const int nt = hi - lo;
  const int q0 = qb << 6;
  const int hk = h >> 2;
  const int qg = q0 + w * 16 + cl;

  const unsigned short* qptr = qkv + (size_t)qg * 3072 + h * 64 + g * 8;
  bf16x8 qf0 = *(const bf16x8*)qptr;
  bf16x8 qf1 = *(const bf16x8*)(qptr + 32);

  float m_run = -3e38f, l_run = 0.0f;
  f32x4 acc[4] = {};

  const unsigned short* kbase = qkv + 2048 + hk * 64;
  const unsigned short* vbase = vt + (size_t)hk * 64 * 2048;
  char* myP = (char*)Ps + w * 2048;

  auto stageK = [&](int ck, int bb) {
    const int kv0 = ck << 6;
#pragma unroll
    for (int it = 0; it < 2; ++it) {
      int cc = tid + it * 256;
      int row = cc >> 3, kb = (cc & 7) << 4;
      const char* src = (const char*)(kbase + (size_t)(kv0 + row) * 3072) + (kb ^ ((row & 7) << 4));
      gload16(src, (char*)Ks[bb] + cc * 16);
    }
  };
  auto stageV = [&](int ck, int bb) {
    const int kv0 = ck << 6;
#pragma unroll
    for (int it = 0; it < 2; ++it) {
      int cc = tid + it * 256;
      int row = cc >> 3, kb = (cc & 7) << 4;
      const char* src = (const char*)(vbase + (size_t)row * 2048 + kv0) + (kb ^ ((row & 7) << 4));
      gload16(src, (char*)Vs[bb] + cc * 16);
    }
  };

  // prologue: tiles lo, lo+1 staged; QK(lo) computed
  stageK(lo, 0); stageV(lo, 0);
  if (nt >= 2) stageK(lo + 1, 1);
  asm volatile("s_waitcnt vmcnt(0)" ::: "memory");
  __syncthreads();

  float svP[4][4];
  {
    const char* Kc = (const char*)Ks[0];
    __builtin_amdgcn_s_setprio(1);
#pragma unroll
    for (int t = 0; t < 4; ++t) {
      f32x4 st = {};
#pragma unroll
      for (int ks = 0; ks < 2; ++ks) {
        int row = t * 16 + cl;
        int kb = ((g << 4) + (ks << 6)) ^ ((row & 7) << 4);
        bf16x8 kf = *(const bf16x8*)(Kc + row * 128 + kb);
        st = __builtin_amdgcn_mfma_f32_16x16x32_bf16(kf, ks ? qf1 : qf0, st, 0, 0, 0);
      }
#pragma unroll
      for (int r = 0; r < 4; ++r) svP[t][r] = st[r];
    }
    __builtin_amdgcn_s_setprio(0);
  }
  __syncthreads();

  for (int i = 0; i < nt; ++i) {
    const int tile = lo + i;
    if (i + 2 < nt) stageK(lo + i + 2, i & 1);
    if (i + 1 < nt) stageV(lo + i + 1, (i + 1) & 1);

    float svN[4][4];
    if (i + 1 < nt) {
      const char* Kc = (const char*)Ks[(i + 1) & 1];
      __builtin_amdgcn_s_setprio(1);
#pragma unroll
      for (int t = 0; t < 4; ++t) {
        f32x4 st = {};
#pragma unroll
        for (int ks = 0; ks < 2; ++ks) {
          int row = t * 16 + cl;
          int kb = ((g << 4) + (ks << 6)) ^ ((row & 7) << 4);
          bf16x8 kf = *(const bf16x8*)(Kc + row * 128 + kb);
          st = __builtin_amdgcn_mfma_f32_16x16x32_bf16(kf, ks ? qf1 : qf0, st, 0, 0, 0);
        }
#pragma unroll
        for (int r = 0; r < 4; ++r) svN[t][r] = st[r];
      }
      __builtin_amdgcn_s_setprio(0);
    }

    if (tile == qb) {  // diagonal: causal mask
      const int kv0 = tile << 6;
#pragma unroll
      for (int t = 0; t < 4; ++t)
#pragma unroll
        for (int r = 0; r < 4; ++r) {
          int kvg = kv0 + t * 16 + (g << 2) + r;
          if (kvg > qg) svP[t][r] = -1e9f;
        }
    }
    float pm[4];
#pragma unroll
    for (int t = 0; t < 4; ++t)
      pm[t] = fmaxf(fmaxf(svP[t][0], svP[t][1]), fmaxf(svP[t][2], svP[t][3]));
    float pmax = fmaxf(fmaxf(pm[0], pm[1]), fmaxf(pm[2], pm[3]));
    pmax = fmaxf(pmax, __shfl_xor(pmax, 16));
    pmax = fmaxf(pmax, __shfl_xor(pmax, 32));
    if (!__all(pmax - m_run <= 8.0f)) {
      float m_new = fmaxf(m_run, pmax);
      float fac = __builtin_exp2f(m_run - m_new);
      float fr[4];
#pragma unroll
      for (int r = 0; r < 4; ++r) fr[r] = __shfl(fac, (g << 2) + r);
#pragma unroll
      for (int t = 0; t < 4; ++t) {
        acc[t][0] *= fr[0]; acc[t][1] *= fr[1]; acc[t][2] *= fr[2]; acc[t][3] *= fr[3];
      }
      l_run *= fac;
      m_run = m_new;
    }
    float ps[4];
#pragma unroll
    for (int t = 0; t < 4; ++t) {
      float e0 = __builtin_exp2f(svP[t][0] - m_run);
      float e1 = __builtin_exp2f(svP[t][1] - m_run);
      float e2 = __builtin_exp2f(svP[t][2] - m_run);
      float e3 = __builtin_exp2f(svP[t][3] - m_run);
      ps[t] = (e0 + e1) + (e2 + e3);
      uint32_t d0, d1;
      asm("v_cvt_pk_bf16_f32 %0, %1, %2" : "=v"(d0) : "v"(e0), "v"(e1));
      asm("v_cvt_pk_bf16_f32 %0, %1, %2" : "=v"(d1) : "v"(e2), "v"(e3));
      uint2 dd; dd.x = d0; dd.y = d1;
      int kb = ((t << 5) + (g << 3)) ^ ((cl & 7) << 4);
      *(uint2*)(myP + cl * 128 + kb) = dd;
    }
    float psum = (ps[0] + ps[1]) + (ps[2] + ps[3]);
    psum += __shfl_xor(psum, 16);
    psum += __shfl_xor(psum, 32);
    l_run += psum;

    {
      const char* Vc = (const char*)Vs[i & 1];
      __builtin_amdgcn_s_setprio(1);
#pragma unroll
      for (int ks = 0; ks < 2; ++ks) {
        int kbp = ((g << 4) + (ks << 6)) ^ ((cl & 7) << 4);
        bf16x8 pf = *(const bf16x8*)(myP + cl * 128 + kbp);
#pragma unroll
        for (int t = 0; t < 4; ++t) {
          int row = t * 16 + cl;
          int kbv = ((g << 4) + (ks << 6)) ^ ((row & 7) << 4);
          bf16x8 vf = *(const bf16x8*)(Vc + row * 128 + kbv);
          acc[t] = __builtin_amdgcn_mfma_f32_16x16x32_bf16(pf, vf, acc[t], 0, 0, 0);
        }
      }
      __builtin_amdgcn_s_setprio(0);
    }

    if (i + 1 < nt) {
      asm volatile("s_waitcnt vmcnt(0)" ::: "memory");
      __syncthreads();
#pragma unroll
      for (int t = 0; t < 4; ++t)
#pragma unroll
        for (int r = 0; r < 4; ++r) svP[t][r] = svN[t][r];
    }
  }

  if (!split) {
    float li[4];
#pragma unroll
    for (int r = 0; r < 4; ++r) li[r] = 1.0f / __shfl(l_run, (g << 2) + r);
#pragma unroll
    for (int t = 0; t < 4; ++t)
#pragma unroll
      for (int r = 0; r < 4; ++r) {
        int row = q0 + w * 16 + (g << 2) + r;
        int col = h * 64 + t * 16 + cl;
        ao[(size_t)row * 2048 + col] = f2bf(acc[t][r] * li[r]);
      }
  } else {
    const int idx = (((h << 4) + (qb - 16)) << 1) + part;
    float* pa = partAcc + (size_t)idx * 4096;
    float* pml = partML + idx * 128;
#pragma unroll
    for (int t = 0; t < 4; ++t)
#pragma unroll
      for (int r = 0; r < 4; ++r)
        pa[(w * 16 + (g << 2) + r) * 64 + t * 16 + cl] = acc[t][r];
    if (g == 0) {
      pml[w * 16 + cl] = m_run;
      pml[64 + w * 16 + cl] = l_run;
    }
  }
}

// ---------------- combine split-KV partials: O = (A0*f0 + A1*f1) / (l0*f0 + l1*f1) ------
__global__ __launch_bounds__(256) void k_combine(const float* __restrict__ partAcc,
                                                 const float* __restrict__ partML,
                                                 unsigned short* __restrict__ ao) {
  const int b = blockIdx.x;  // 512 = 32h x 16 qbIdx
  const int h = b & 31, qi = b >> 5;
  const int qb = 16 + qi;
  const int base = (((h << 4) + qi) << 1);
  const float* a0 = partAcc + (size_t)base * 4096;
  const float* a1 = a0 + 4096;
  const float* ml0 = partML + base * 128;
  const float* ml1 = ml0 + 128;
  const int t = threadIdx.x;
  const int q = t >> 2, d0 = (t & 3) << 4;
  float m0 = ml0[q], m1 = ml1[q], l0 = ml0[64 + q], l1 = ml1[64 + q];
  float m = fmaxf(m0, m1);
  float f0 = __builtin_exp2f(m0 - m), f1 = __builtin_exp2f(m1 - m);
  float li = 1.0f / (l0 * f0 + l1 * f1);
  unsigned short tmp[16] __attribute__((aligned(16)));
#pragma unroll
  for (int j = 0; j < 16; j += 4) {
    float4 v0 = *(const float4*)(a0 + q * 64 + d0 + j);
    float4 v1 = *(const float4*)(a1 + q * 64 + d0 + j);
    tmp[j + 0] = f2bf((v0.x * f0 + v1.x * f1) * li);
    tmp[j + 1] = f2bf((v0.y * f0 + v1.y * f1) * li);
    tmp[j + 2] = f2bf((v0.z * f0 + v1.z * f1) * li);
    tmp[j + 3] = f2bf((v0.w * f0 + v1.w * f1) * li);
  }
  size_t orow = (size_t)(qb * 64 + q) * 2048 + h * 64 + d0;
  *(uint4*)(ao + orow) = *(const uint4*)tmp;
  *(uint4*)(ao + orow + 8) = *(const uint4*)(tmp + 8);
}

extern "C" void kernel_launch(void* const* d_in, const int* in_sizes, int n_in,
                              void* d_out, int out_size, void* d_ws, size_t ws_size,
                              hipStream_t stream) {
  (void)in_sizes; (void)n_in; (void)out_size; (void)ws_size;
  const float* x  = (const float*)d_in[0];
  const float* sc = (const float*)d_in[1];
  // d_in[2] = mask (causal, applied analytically)
  const float* Wq = (const float*)d_in[3];
  const float* Wk = (const float*)d_in[4];
  const float* Wv = (const float*)d_in[5];
  const float* Wo = (const float*)d_in[6];
  float* out = (float*)d_out;
  char* ws = (char*)d_ws;
  unsigned short* xb   = (unsigned short*)(ws);              // 8 MB   (reused as partials after gemm0)
  unsigned short* Wcat = (unsigned short*)(ws + 8388608);    // 12 MB  [3072][2048]
  unsigned short* Wob  = (unsigned short*)(ws + 20971520);   // 8 MB
  unsigned short* QKV  = (unsigned short*)(ws + 29360128);   // 12 MB  [2048][3072]
  unsigned short* VT   = (unsigned short*)(ws + 41943040);   // 2 MB   [8][64][2048]
  unsigned short* AO   = (unsigned short*)(ws + 44040192);   // 8 MB   [2048][2048]
  // split-KV partials overlay xb/Wcat (dead after gemm0): 16 MB + 0.5 MB
  float* partAcc = (float*)(ws);
  float* partML  = (float*)(ws + 16777216);

  k_cvt_all<<<14336, 256, 0, stream>>>(x, Wq, Wk, Wv, Wo, xb, Wcat, Wob);
  k_gemm<0, 1><<<384, 256, 0, stream>>>(xb, Wcat, QKV, 2048, 3072, 2048, sc);  // +RoPE epilogue
  k_vt<<<256, 256, 0, stream>>>(QKV, VT);
  k_attn<<<1536, 256, 0, stream>>>(QKV, VT, AO, partAcc, partML);
  k_combine<<<512, 256, 0, stream>>>(partAcc, partML, AO);
  k_gemm<1, 0><<<256, 256, 0, stream>>>(AO, Wob, out, 2048, 2048, 2048, nullptr);
}